// Round 11
// baseline (83.379 us; speedup 1.0000x reference)
//
#include <hip/hip_runtime.h>
#include <stdint.h>

typedef __attribute__((ext_vector_type(8))) short bf16x8;
typedef __attribute__((ext_vector_type(4))) float f32x4;
typedef __attribute__((ext_vector_type(2))) float f32x2;

__device__ inline float bflo(uint32_t w) { union { uint32_t i; float f; } v; v.i = w << 16; return v.f; }
__device__ inline float bfhi(uint32_t w) { union { uint32_t i; float f; } v; v.i = w & 0xffff0000u; return v.f; }
__device__ inline uint32_t f2bf(float f) { union { float f; uint32_t i; } v; v.f = f; return (v.i + 0x8000u) >> 16; }
__device__ inline uint32_t pk(float lo, float hi) { return f2bf(lo) | (f2bf(hi) << 16); }

// packed 2xf32 add/sub (VOP3P), and packed f32->bf16 convert (gfx950)
__device__ inline f32x2 pka(f32x2 a, f32x2 b) {
    f32x2 d; asm("v_pk_add_f32 %0, %1, %2" : "=v"(d) : "v"(a), "v"(b)); return d;
}
__device__ inline f32x2 pks(f32x2 a, f32x2 b) {
    f32x2 d; asm("v_pk_add_f32 %0, %1, %2 neg_lo:[0,1] neg_hi:[0,1]" : "=v"(d) : "v"(a), "v"(b)); return d;
}
__device__ inline uint32_t cvtpk2(float lo, float hi) {
    uint32_t r; asm("v_cvt_pk_bf16_f32 %0, %1, %2" : "=v"(r) : "v"(lo), "v"(hi)); return r;
}
__device__ inline uint32_t cvtpk(f32x2 v) { return cvtpk2(v.x, v.y); }

// ---------------- Filter transform: U = G K G^T -> d_ws (bf16, frag-major) ----------------
// Layout (u16): U[pos=16][cblk=4][f=32][c7=8]; as u32: [pos][cblk*32+f][cpair2]
__global__ __launch_bounds__(256) void wg_filter(const float* __restrict__ Kk, uint32_t* __restrict__ Ud)
{
    const int idx = blockIdx.x * 256 + threadIdx.x;   // 0..511
    if (idx >= 512) return;
    const int cp = idx & 15, f = idx >> 4;
    float u[2][16];
    #pragma unroll
    for (int h = 0; h < 2; h++) {
        const float* kp = Kk + (f * 32 + cp * 2 + h) * 9;
        float k00 = kp[0], k01 = kp[1], k02 = kp[2];
        float k10 = kp[3], k11 = kp[4], k12 = kp[5];
        float k20 = kp[6], k21 = kp[7], k22 = kp[8];
        float t[4][3];
        t[0][0] = k00; t[0][1] = k01; t[0][2] = k02;
        t[1][0] = 0.5f * (k00 + k10 + k20); t[1][1] = 0.5f * (k01 + k11 + k21); t[1][2] = 0.5f * (k02 + k12 + k22);
        t[2][0] = 0.5f * (k00 - k10 + k20); t[2][1] = 0.5f * (k01 - k11 + k21); t[2][2] = 0.5f * (k02 - k12 + k22);
        t[3][0] = k20; t[3][1] = k21; t[3][2] = k22;
        #pragma unroll
        for (int i = 0; i < 4; i++) {
            float a0 = t[i][0], a1 = t[i][1], a2 = t[i][2];
            u[h][i * 4 + 0] = a0;
            u[h][i * 4 + 1] = 0.5f * (a0 + a1 + a2);
            u[h][i * 4 + 2] = 0.5f * (a0 - a1 + a2);
            u[h][i * 4 + 3] = a2;
        }
    }
    const int base = ((cp >> 2) * 32 + f) * 4 + (cp & 3);
    #pragma unroll
    for (int p = 0; p < 16; p++) Ud[p * 512 + base] = pk(u[0][p], u[1][p]);
}

// ---------------- Main fused kernel ----------------
// Block: 256 threads, 32 tiles (4 tile-rows x 8 tile-cols), 8192 blocks.
// R10 + f32 patch staging: patch lives in LDS as float2 channel-pairs ->
// C-phase has ZERO unpack VALU (was ~128 instrs/thread); staging writes one
// aligned b128 (no cvt_pk). V stays bf16. LDS 23296+16384=39680 B -> 4 blocks/CU.
__global__ __launch_bounds__(256, 3) void wg_main(
    const float* __restrict__ X, const uint16_t* __restrict__ U, float* __restrict__ out)
{
    // f32 channel-pair patch: Pl[pair=16][row=10][col=18] float2, plane stride 182
    __shared__ __align__(16) float2 Pl[2912];
    // V double-buffer: V[2][l=4][tblk=2][cblk=4][t15=16][c7=8] bf16, 2 x 8 KB
    __shared__ __align__(16) uint16_t Vl[2][4096];

    const int tid = threadIdx.x;
    // XCD-chunked bijective swizzle (8192 blocks % 8 == 0)
    const int lin  = blockIdx.x + 16 * (blockIdx.y + 32 * blockIdx.z);
    const int work = (lin & 7) * 1024 + (lin >> 3);
    const int qb = work & 15;          // tile col base qb*8
    const int pb = (work >> 4) & 31;   // tile row base pb*4
    const int b  = work >> 9;
    const int y0 = pb * 8, x0 = qb * 16;

    const int wave = tid >> 6, lane = tid & 63;
    const int fh = wave & 1, tb = wave >> 1;
    const int l15 = lane & 15, lq = lane >> 4;
    const uint16_t* Ub = U + (lq * 32 + fh * 16 + l15) * 8;

    // prefetch chunk 0's U fragments (latency hidden under X staging)
    bf16x8 a_cur[4];
    #pragma unroll
    for (int l = 0; l < 4; l++)
        a_cur[l] = *(const bf16x8*)(Ub + l * 1024);

    // ---- Phase B: stage 10x18 patch as f32 channel pairs, b128 stores ----
    for (int s = tid; s < 1440; s += 256) {
        const int pr = s / 90;
        const int r  = s - pr * 90;
        const int row = r / 9, seg = r - row * 9;
        const float* g0 = X + ((size_t)((b * 32 + pr * 2) * 258 + y0 + row)) * 258 + x0 + seg * 2;
        float2 a = *(const float2*)g0;
        float2 c = *(const float2*)(g0 + 258 * 258);
        float4 w = make_float4(a.x, c.x, a.y, c.y);   // {pair@col0, pair@col1}
        *(float4*)&Pl[pr * 182 + row * 18 + seg * 2] = w;
    }
    __syncthreads();

    // per-thread C-phase indices (constant across chunks)
    const int cp2 = tid & 3, t15c = (tid >> 2) & 15;

    float y[4][4];
    #pragma unroll
    for (int r = 0; r < 4; r++)
        #pragma unroll
        for (int j = 0; j < 4; j++) y[r][j] = 0.f;

    // ---- Chunk loop over B^T rows i=0..3 (4 positions each) ----
    #pragma unroll
    for (int i = 0; i < 4; i++) {
        // rows (ra,rb) and op for bt_i: i0: d0-d2; i1: d1+d2; i2: d2-d1; i3: d1-d3
        const int ra = (i == 0) ? 0 : (i == 2) ? 2 : 1;
        const int rb = (i == 3) ? 3 : (i == 2) ? 1 : 2;

        uint32_t* vp = (uint32_t*)Vl[i & 1];

        // Phase C(i): V row i (4 positions) from 2 patch rows -> Vl[i&1]
        #pragma unroll
        for (int it = 0; it < 2; it++) {
            const int rem  = it * 4 + wave;
            const int tblk = rem & 1, cpH = rem >> 1;
            const int cp   = cpH * 4 + cp2;
            const int tt   = tblk * 16 + t15c;
            const int tr   = tt >> 3, tc = tt & 7;
            const float2* pp = &Pl[cp * 182 + (tr * 2) * 18 + tc * 2];
            float4 wa0 = *(const float4*)(pp + ra * 18);       // pairs @ cols 0,1
            float4 wa1 = *(const float4*)(pp + ra * 18 + 2);   // pairs @ cols 2,3
            float4 wb0 = *(const float4*)(pp + rb * 18);
            float4 wb1 = *(const float4*)(pp + rb * 18 + 2);
            f32x2 da[4], db[4];
            da[0] = (f32x2){wa0.x, wa0.y}; da[1] = (f32x2){wa0.z, wa0.w};
            da[2] = (f32x2){wa1.x, wa1.y}; da[3] = (f32x2){wa1.z, wa1.w};
            db[0] = (f32x2){wb0.x, wb0.y}; db[1] = (f32x2){wb0.z, wb0.w};
            db[2] = (f32x2){wb1.x, wb1.y}; db[3] = (f32x2){wb1.z, wb1.w};
            f32x2 e[4];
            #pragma unroll
            for (int k = 0; k < 4; k++)
                e[k] = (i == 1) ? pka(da[k], db[k]) : pks(da[k], db[k]);
            const int vbase = ((tblk * 4 + cpH) * 16 + t15c) * 4 + cp2;
            vp[0 * 512 + vbase] = cvtpk(pks(e[0], e[2]));
            vp[1 * 512 + vbase] = cvtpk(pka(e[1], e[2]));
            vp[2 * 512 + vbase] = cvtpk(pks(e[2], e[1]));
            vp[3 * 512 + vbase] = cvtpk(pks(e[1], e[3]));
        }

        // prefetch next chunk's U fragments (latency hides under barrier + ds_reads)
        bf16x8 a_nxt[4];
        if (i < 3) {
            #pragma unroll
            for (int l = 0; l < 4; l++)
                a_nxt[l] = *(const bf16x8*)(Ub + ((i + 1) * 4 + l) * 1024);
        }

        __syncthreads();   // Vl[i&1] ready

        // Phase D(i): 4 MFMAs from Vl[i&1] with prefetched a_cur.
        const uint16_t* Vb = Vl[i & 1] + ((tb * 4 + lq) * 16 + l15) * 8;
        f32x4 acc[4];
        #pragma unroll
        for (int l = 0; l < 4; l++) {
            bf16x8 v = *(const bf16x8*)(Vb + l * 1024);
            acc[l] = __builtin_amdgcn_mfma_f32_16x16x32_bf16(a_cur[l], v,
                        (f32x4){0.f, 0.f, 0.f, 0.f}, 0, 0, 0);
        }

        #pragma unroll
        for (int l = 0; l < 4; l++) a_cur[l] = a_nxt[l];

        // incremental A^T fold of this chunk (one B^T row i)
        #pragma unroll
        for (int r = 0; r < 4; r++) {
            float m0 = acc[0][r], m1 = acc[1][r], m2 = acc[2][r], m3 = acc[3][r];
            float c0 = m0 + m1 + m2, c1 = m1 - m2 - m3;
            if (i == 0)      { y[r][0] += c0; y[r][1] += c1; }
            else if (i == 1) { y[r][0] += c0; y[r][1] += c1; y[r][2] += c0; y[r][3] += c1; }
            else if (i == 2) { y[r][0] += c0; y[r][1] += c1; y[r][2] -= c0; y[r][3] -= c1; }
            else             { y[r][2] -= c0; y[r][3] -= c1; }
        }
    }

    // ---- Store ----
    const int tt = tb * 16 + l15;
    const int trr = tt >> 3, tcc = tt & 7;
    const int p = pb * 4 + trr, q = qb * 8 + tcc;
    #pragma unroll
    for (int r = 0; r < 4; r++) {
        const int f = fh * 16 + lq * 4 + r;
        float* op = out + ((size_t)(b * 32 + f) * 256 + 2 * p) * 256 + 2 * q;
        *(float2*)op = make_float2(y[r][0], y[r][1]);
        *(float2*)(op + 256) = make_float2(y[r][2], y[r][3]);
    }
}

// ---------------- Fallback (monolithic) if ws is too small ----------------
__device__ inline uint16_t f2bf16_rne(float f) {
    union { float f; uint32_t i; } v; v.f = f;
    uint32_t x = v.i;
    uint32_t r = x + 0x7fffu + ((x >> 16) & 1u);
    return (uint16_t)(r >> 16);
}
__global__ __launch_bounds__(256) void winograd_fallback(
    const float* __restrict__ X, const float* __restrict__ K, float* __restrict__ out)
{
    __shared__ uint16_t Ul[16384];
    __shared__ uint16_t Vl[16384];
    __shared__ uint16_t Pl[32 * 242];
    const int tid = threadIdx.x;
    const int qb = blockIdx.x, pb = blockIdx.y, b = blockIdx.z;
    for (int idx = tid; idx < 1024; idx += 256) {
        const int f = idx >> 5, c = idx & 31;
        const float* kp = K + (f * 32 + c) * 9;
        float k00 = kp[0], k01 = kp[1], k02 = kp[2];
        float k10 = kp[3], k11 = kp[4], k12 = kp[5];
        float k20 = kp[6], k21 = kp[7], k22 = kp[8];
        float t[4][3];
        t[0][0] = k00; t[0][1] = k01; t[0][2] = k02;
        t[1][0] = 0.5f * (k00 + k10 + k20); t[1][1] = 0.5f * (k01 + k11 + k21); t[1][2] = 0.5f * (k02 + k12 + k22);
        t[2][0] = 0.5f * (k00 - k10 + k20); t[2][1] = 0.5f * (k01 - k11 + k21); t[2][2] = 0.5f * (k02 - k12 + k22);
        t[3][0] = k20; t[3][1] = k21; t[3][2] = k22;
        const int ubase = ((c >> 3) * 32 + f) * 8 + (c & 7);
        #pragma unroll
        for (int i = 0; i < 4; i++) {
            float a0 = t[i][0], a1 = t[i][1], a2 = t[i][2];
            Ul[(i * 4 + 0) * 1024 + ubase] = f2bf16_rne(a0);
            Ul[(i * 4 + 1) * 1024 + ubase] = f2bf16_rne(0.5f * (a0 + a1 + a2));
            Ul[(i * 4 + 2) * 1024 + ubase] = f2bf16_rne(0.5f * (a0 - a1 + a2));
            Ul[(i * 4 + 3) * 1024 + ubase] = f2bf16_rne(a2);
        }
    }
    const int y0 = pb * 8, x0 = qb * 16;
    for (int s = tid; s < 2880; s += 256) {
        const int c = s / 90;
        const int r = s % 90;
        const int row = r / 9, seg = r % 9;
        const float* gp = X + ((b * 32 + c) * 258 + (y0 + row)) * 258 + x0 + seg * 2;
        float2 g = *(const float2*)gp;
        uint32_t packed = (uint32_t)f2bf16_rne(g.x) | ((uint32_t)f2bf16_rne(g.y) << 16);
        *(uint32_t*)&Pl[c * 242 + row * 24 + seg * 2] = packed;
    }
    __syncthreads();
    for (int idx = tid; idx < 1024; idx += 256) {
        const int c = idx & 31, tt = idx >> 5;
        const int tr = tt >> 3, tc = tt & 7;
        const uint16_t* pp = &Pl[c * 242 + (tr * 2) * 24 + tc * 2];
        float d[4][4];
        #pragma unroll
        for (int j = 0; j < 4; j++) {
            uint32_t w0 = *(const uint32_t*)&pp[j * 24];
            uint32_t w1 = *(const uint32_t*)&pp[j * 24 + 2];
            d[j][0] = bflo(w0); d[j][1] = bfhi(w0);
            d[j][2] = bflo(w1); d[j][3] = bfhi(w1);
        }
        float bt[4][4];
        #pragma unroll
        for (int k = 0; k < 4; k++) {
            bt[0][k] = d[0][k] - d[2][k];
            bt[1][k] = d[1][k] + d[2][k];
            bt[2][k] = d[2][k] - d[1][k];
            bt[3][k] = d[1][k] - d[3][k];
        }
        const int vbase = (((tt >> 4) * 4 + (c >> 3)) * 16 + (tt & 15)) * 8 + (c & 7);
        #pragma unroll
        for (int i = 0; i < 4; i++) {
            float b0 = bt[i][0], b1 = bt[i][1], b2 = bt[i][2], b3 = bt[i][3];
            Vl[(i * 4 + 0) * 1024 + vbase] = f2bf16_rne(b0 - b2);
            Vl[(i * 4 + 1) * 1024 + vbase] = f2bf16_rne(b1 + b2);
            Vl[(i * 4 + 2) * 1024 + vbase] = f2bf16_rne(b2 - b1);
            Vl[(i * 4 + 3) * 1024 + vbase] = f2bf16_rne(b1 - b3);
        }
    }
    __syncthreads();
    const int wave = tid >> 6, lane = tid & 63;
    const int fh = wave & 1, tb = wave >> 1;
    const int l15 = lane & 15, lq = lane >> 4;
    f32x4 acc[16];
    #pragma unroll
    for (int p = 0; p < 16; p++) acc[p] = (f32x4){0.f, 0.f, 0.f, 0.f};
    #pragma unroll
    for (int p = 0; p < 16; p++) {
        bf16x8 a = *(const bf16x8*)&Ul[p * 1024 + (lq * 32 + fh * 16 + l15) * 8];
        bf16x8 bv = *(const bf16x8*)&Vl[p * 1024 + ((tb * 4 + lq) * 16 + l15) * 8];
        acc[p] = __builtin_amdgcn_mfma_f32_16x16x32_bf16(a, bv, acc[p], 0, 0, 0);
    }
    #pragma unroll
    for (int r = 0; r < 4; r++) {
        const int f = fh * 16 + lq * 4 + r;
        const int t = tb * 16 + l15;
        const int tr = t >> 3, tc = t & 7;
        const int p = pb * 4 + tr, q = qb * 8 + tc;
        float m[4][4];
        #pragma unroll
        for (int i = 0; i < 4; i++)
            #pragma unroll
            for (int l = 0; l < 4; l++)
                m[i][l] = acc[i * 4 + l][r];
        float s0[4], s1[4];
        #pragma unroll
        for (int k = 0; k < 4; k++) {
            s0[k] = m[0][k] + m[1][k] + m[2][k];
            s1[k] = m[1][k] - m[2][k] - m[3][k];
        }
        float* op = out + ((size_t)(b * 32 + f) * 256 + 2 * p) * 256 + 2 * q;
        *(float2*)op = make_float2(s0[0] + s0[1] + s0[2], s0[1] - s0[2] - s0[3]);
        *(float2*)(op + 256) = make_float2(s1[0] + s1[1] + s1[2], s1[1] - s1[2] - s1[3]);
    }
}

extern "C" void kernel_launch(void* const* d_in, const int* in_sizes, int n_in,
                              void* d_out, int out_size, void* d_ws, size_t ws_size,
                              hipStream_t stream) {
    const float* X = (const float*)d_in[0];
    const float* K = (const float*)d_in[1];
    float* out = (float*)d_out;
    dim3 grid(16, 32, 16);
    if (ws_size >= 32768) {
        wg_filter<<<2, 256, 0, stream>>>(K, (uint32_t*)d_ws);
        wg_main<<<grid, 256, 0, stream>>>(X, (const uint16_t*)d_ws, out);
    } else {
        winograd_fallback<<<grid, 256, 0, stream>>>(X, K, out);
    }
}

// Round 12
// 79.900 us; speedup vs baseline: 1.0435x; 1.0435x over previous
//
#include <hip/hip_runtime.h>
#include <stdint.h>

typedef __attribute__((ext_vector_type(8))) short bf16x8;
typedef __attribute__((ext_vector_type(4))) float f32x4;
typedef __attribute__((ext_vector_type(2))) float f32x2;

__device__ inline float bflo(uint32_t w) { union { uint32_t i; float f; } v; v.i = w << 16; return v.f; }
__device__ inline float bfhi(uint32_t w) { union { uint32_t i; float f; } v; v.i = w & 0xffff0000u; return v.f; }
__device__ inline uint32_t f2bf(float f) { union { float f; uint32_t i; } v; v.f = f; return (v.i + 0x8000u) >> 16; }
__device__ inline uint32_t pk(float lo, float hi) { return f2bf(lo) | (f2bf(hi) << 16); }

// packed 2xf32 add/sub (VOP3P), and packed f32->bf16 convert (gfx950)
__device__ inline f32x2 pka(f32x2 a, f32x2 b) {
    f32x2 d; asm("v_pk_add_f32 %0, %1, %2" : "=v"(d) : "v"(a), "v"(b)); return d;
}
__device__ inline f32x2 pks(f32x2 a, f32x2 b) {
    f32x2 d; asm("v_pk_add_f32 %0, %1, %2 neg_lo:[0,1] neg_hi:[0,1]" : "=v"(d) : "v"(a), "v"(b)); return d;
}
__device__ inline uint32_t cvtpk2(float lo, float hi) {
    uint32_t r; asm("v_cvt_pk_bf16_f32 %0, %1, %2" : "=v"(r) : "v"(lo), "v"(hi)); return r;
}
__device__ inline uint32_t cvtpk(f32x2 v) { return cvtpk2(v.x, v.y); }
__device__ inline f32x2 unpk(uint32_t w) {
    union { uint32_t u; float f; } lo, hi; lo.u = w << 16; hi.u = w & 0xffff0000u;
    return (f32x2){lo.f, hi.f};
}

// ---------------- Filter transform: U = G K G^T -> d_ws (bf16, frag-major) ----------------
// Layout (u16): U[pos=16][cblk=4][f=32][c7=8]; as u32: [pos][cblk*32+f][cpair2]
__global__ __launch_bounds__(256) void wg_filter(const float* __restrict__ Kk, uint32_t* __restrict__ Ud)
{
    const int idx = blockIdx.x * 256 + threadIdx.x;   // 0..511
    if (idx >= 512) return;
    const int cp = idx & 15, f = idx >> 4;
    float u[2][16];
    #pragma unroll
    for (int h = 0; h < 2; h++) {
        const float* kp = Kk + (f * 32 + cp * 2 + h) * 9;
        float k00 = kp[0], k01 = kp[1], k02 = kp[2];
        float k10 = kp[3], k11 = kp[4], k12 = kp[5];
        float k20 = kp[6], k21 = kp[7], k22 = kp[8];
        float t[4][3];
        t[0][0] = k00; t[0][1] = k01; t[0][2] = k02;
        t[1][0] = 0.5f * (k00 + k10 + k20); t[1][1] = 0.5f * (k01 + k11 + k21); t[1][2] = 0.5f * (k02 + k12 + k22);
        t[2][0] = 0.5f * (k00 - k10 + k20); t[2][1] = 0.5f * (k01 - k11 + k21); t[2][2] = 0.5f * (k02 - k12 + k22);
        t[3][0] = k20; t[3][1] = k21; t[3][2] = k22;
        #pragma unroll
        for (int i = 0; i < 4; i++) {
            float a0 = t[i][0], a1 = t[i][1], a2 = t[i][2];
            u[h][i * 4 + 0] = a0;
            u[h][i * 4 + 1] = 0.5f * (a0 + a1 + a2);
            u[h][i * 4 + 2] = 0.5f * (a0 - a1 + a2);
            u[h][i * 4 + 3] = a2;
        }
    }
    const int base = ((cp >> 2) * 32 + f) * 4 + (cp & 3);
    #pragma unroll
    for (int p = 0; p < 16; p++) Ud[p * 512 + base] = pk(u[0][p], u[1][p]);
}

// D-phase: 4 MFMAs from one V buffer + chunk-specific incremental A^T fold
template<int CH>
__device__ __forceinline__ void d_phase(const uint16_t* __restrict__ Vbuf,
                                        const bf16x8 (&a)[4], float (&y)[4][4],
                                        int tb, int lq, int l15)
{
    const uint16_t* Vb = Vbuf + ((tb * 4 + lq) * 16 + l15) * 8;
    f32x4 acc[4];
    #pragma unroll
    for (int l = 0; l < 4; l++) {
        bf16x8 v = *(const bf16x8*)(Vb + l * 1024);
        acc[l] = __builtin_amdgcn_mfma_f32_16x16x32_bf16(a[l], v,
                    (f32x4){0.f, 0.f, 0.f, 0.f}, 0, 0, 0);
    }
    #pragma unroll
    for (int r = 0; r < 4; r++) {
        float m0 = acc[0][r], m1 = acc[1][r], m2 = acc[2][r], m3 = acc[3][r];
        float c0 = m0 + m1 + m2, c1 = m1 - m2 - m3;
        if (CH == 0)      { y[r][0] += c0; y[r][1] += c1; }
        else if (CH == 1) { y[r][0] += c0; y[r][1] += c1; y[r][2] += c0; y[r][3] += c1; }
        else if (CH == 2) { y[r][0] += c0; y[r][1] += c1; y[r][2] -= c0; y[r][3] -= c1; }
        else              { y[r][2] -= c0; y[r][3] -= c1; }
    }
}

// ---------------- Main fused kernel ----------------
// Block: 256 threads, 32 tiles (4 tile-rows x 8 tile-cols), 8192 blocks.
// Fused single-pass C: read patch rows 0-3 ONCE (halves C-phase LDS reads and
// bf16 unpack VALU), compute all 4 chunks' V; write chunk0->Vl[0], chunk2->Vl[1]
// now, hold chunks 1,3 in 16 regs. D order (0,2),(1,3): 4 barriers total.
// LDS 11648 + 16384 = 28032 B -> 5 blocks/CU; launch_bounds(256,3) -> 85-reg budget.
__global__ __launch_bounds__(256, 3) void wg_main(
    const float* __restrict__ X, const uint16_t* __restrict__ U, float* __restrict__ out)
{
    // packed channel-pair patch: Pl[pair=16][row=10][col=18] u32, plane stride 182
    __shared__ __align__(16) uint32_t Pl[2912];
    // V double-buffer: V[2][l=4][tblk=2][cblk=4][t15=16][c7=8] bf16, 2 x 8 KB
    __shared__ __align__(16) uint16_t Vl[2][4096];

    const int tid = threadIdx.x;
    // XCD-chunked bijective swizzle (8192 blocks % 8 == 0)
    const int lin  = blockIdx.x + 16 * (blockIdx.y + 32 * blockIdx.z);
    const int work = (lin & 7) * 1024 + (lin >> 3);
    const int qb = work & 15;          // tile col base qb*8
    const int pb = (work >> 4) & 31;   // tile row base pb*4
    const int b  = work >> 9;
    const int y0 = pb * 8, x0 = qb * 16;

    const int wave = tid >> 6, lane = tid & 63;
    const int fh = wave & 1, tb = wave >> 1;
    const int l15 = lane & 15, lq = lane >> 4;
    const uint16_t* Ub = U + (lq * 32 + fh * 16 + l15) * 8;

    // prefetch chunk0's U fragments (hidden under X staging)
    bf16x8 a_cur[4], a_nxt[4];
    #pragma unroll
    for (int l = 0; l < 4; l++)
        a_cur[l] = *(const bf16x8*)(Ub + l * 1024);

    // ---- Phase B: stage 10x18 patch, channel pairs packed in u32 ----
    for (int s = tid; s < 1440; s += 256) {
        const int pr = s / 90;
        const int r  = s - pr * 90;
        const int row = r / 9, seg = r - row * 9;
        const float* g0 = X + ((size_t)((b * 32 + pr * 2) * 258 + y0 + row)) * 258 + x0 + seg * 2;
        float2 a = *(const float2*)g0;
        float2 c = *(const float2*)(g0 + 258 * 258);
        uint2 w;
        w.x = cvtpk2(a.x, c.x);
        w.y = cvtpk2(a.y, c.y);
        *(uint2*)&Pl[pr * 182 + row * 18 + seg * 2] = w;
    }
    // prefetch chunk2's U fragments (hidden under barrier drain + C_all)
    #pragma unroll
    for (int l = 0; l < 4; l++)
        a_nxt[l] = *(const bf16x8*)(Ub + (2 * 4 + l) * 1024);
    __syncthreads();

    const int cp2 = tid & 3, t15c = (tid >> 2) & 15;

    float y[4][4];
    #pragma unroll
    for (int r = 0; r < 4; r++)
        #pragma unroll
        for (int j = 0; j < 4; j++) y[r][j] = 0.f;

    uint32_t vh1[2][4], vh3[2][4];   // held V for chunks 1,3 (written later)
    int vbs[2];
    uint32_t* vp0 = (uint32_t*)Vl[0];
    uint32_t* vp1 = (uint32_t*)Vl[1];

    // ---- Fused C: read rows 0-3 once, compute V for all 4 chunks ----
    #pragma unroll
    for (int it = 0; it < 2; it++) {
        const int rem  = it * 4 + wave;
        const int tblk = rem & 1, cpH = rem >> 1;
        const int cp   = cpH * 4 + cp2;
        const int tt   = tblk * 16 + t15c;
        const int tr   = tt >> 3, tc = tt & 7;
        const uint32_t* pp = &Pl[cp * 182 + (tr * 2) * 18 + tc * 2];
        f32x2 d[4][4];
        #pragma unroll
        for (int j = 0; j < 4; j++) {
            uint2 w0 = *(const uint2*)&pp[j * 18];
            uint2 w1 = *(const uint2*)&pp[j * 18 + 2];
            d[j][0] = unpk(w0.x); d[j][1] = unpk(w0.y);
            d[j][2] = unpk(w1.x); d[j][3] = unpk(w1.y);
        }
        f32x2 e0[4], e1[4], e2[4], e3[4];
        #pragma unroll
        for (int k = 0; k < 4; k++) {
            e0[k] = pks(d[0][k], d[2][k]);   // bt row 0
            e1[k] = pka(d[1][k], d[2][k]);   // bt row 1
            e2[k] = pks(d[2][k], d[1][k]);   // bt row 2
            e3[k] = pks(d[1][k], d[3][k]);   // bt row 3
        }
        const int vbase = ((tblk * 4 + cpH) * 16 + t15c) * 4 + cp2;
        vbs[it] = vbase;
        // chunk0 -> Vl[0] now
        vp0[0 * 512 + vbase] = cvtpk(pks(e0[0], e0[2]));
        vp0[1 * 512 + vbase] = cvtpk(pka(e0[1], e0[2]));
        vp0[2 * 512 + vbase] = cvtpk(pks(e0[2], e0[1]));
        vp0[3 * 512 + vbase] = cvtpk(pks(e0[1], e0[3]));
        // chunk2 -> Vl[1] now
        vp1[0 * 512 + vbase] = cvtpk(pks(e2[0], e2[2]));
        vp1[1 * 512 + vbase] = cvtpk(pka(e2[1], e2[2]));
        vp1[2 * 512 + vbase] = cvtpk(pks(e2[2], e2[1]));
        vp1[3 * 512 + vbase] = cvtpk(pks(e2[1], e2[3]));
        // chunks 1,3 -> registers
        vh1[it][0] = cvtpk(pks(e1[0], e1[2]));
        vh1[it][1] = cvtpk(pka(e1[1], e1[2]));
        vh1[it][2] = cvtpk(pks(e1[2], e1[1]));
        vh1[it][3] = cvtpk(pks(e1[1], e1[3]));
        vh3[it][0] = cvtpk(pks(e3[0], e3[2]));
        vh3[it][1] = cvtpk(pka(e3[1], e3[2]));
        vh3[it][2] = cvtpk(pks(e3[2], e3[1]));
        vh3[it][3] = cvtpk(pks(e3[1], e3[3]));
    }
    __syncthreads();   // Vl[0]=chunk0, Vl[1]=chunk2 ready

    // ---- D(0) from Vl[0], D(2) from Vl[1] ----
    d_phase<0>(Vl[0], a_cur, y, tb, lq, l15);
    #pragma unroll
    for (int l = 0; l < 4; l++) a_cur[l] = a_nxt[l];              // -> chunk2
    #pragma unroll
    for (int l = 0; l < 4; l++)
        a_nxt[l] = *(const bf16x8*)(Ub + (1 * 4 + l) * 1024);     // prefetch chunk1
    d_phase<2>(Vl[1], a_cur, y, tb, lq, l15);
    #pragma unroll
    for (int l = 0; l < 4; l++) a_cur[l] = a_nxt[l];              // -> chunk1
    #pragma unroll
    for (int l = 0; l < 4; l++)
        a_nxt[l] = *(const bf16x8*)(Ub + (3 * 4 + l) * 1024);     // prefetch chunk3

    __syncthreads();   // all waves finished reading Vl[0]/Vl[1]

    // ---- write held chunks: 1 -> Vl[0], 3 -> Vl[1] ----
    #pragma unroll
    for (int it = 0; it < 2; it++) {
        #pragma unroll
        for (int l = 0; l < 4; l++) {
            vp0[l * 512 + vbs[it]] = vh1[it][l];
            vp1[l * 512 + vbs[it]] = vh3[it][l];
        }
    }
    __syncthreads();   // Vl[0]=chunk1, Vl[1]=chunk3 ready

    // ---- D(1) from Vl[0], D(3) from Vl[1] ----
    d_phase<1>(Vl[0], a_cur, y, tb, lq, l15);
    #pragma unroll
    for (int l = 0; l < 4; l++) a_cur[l] = a_nxt[l];              // -> chunk3
    d_phase<3>(Vl[1], a_cur, y, tb, lq, l15);

    // ---- Store ----
    const int tt = tb * 16 + l15;
    const int trr = tt >> 3, tcc = tt & 7;
    const int p = pb * 4 + trr, q = qb * 8 + tcc;
    #pragma unroll
    for (int r = 0; r < 4; r++) {
        const int f = fh * 16 + lq * 4 + r;
        float* op = out + ((size_t)(b * 32 + f) * 256 + 2 * p) * 256 + 2 * q;
        *(float2*)op = make_float2(y[r][0], y[r][1]);
        *(float2*)(op + 256) = make_float2(y[r][2], y[r][3]);
    }
}

// ---------------- Fallback (monolithic) if ws is too small ----------------
__device__ inline uint16_t f2bf16_rne(float f) {
    union { float f; uint32_t i; } v; v.f = f;
    uint32_t x = v.i;
    uint32_t r = x + 0x7fffu + ((x >> 16) & 1u);
    return (uint16_t)(r >> 16);
}
__global__ __launch_bounds__(256) void winograd_fallback(
    const float* __restrict__ X, const float* __restrict__ K, float* __restrict__ out)
{
    __shared__ uint16_t Ul[16384];
    __shared__ uint16_t Vl[16384];
    __shared__ uint16_t Pl[32 * 242];
    const int tid = threadIdx.x;
    const int qb = blockIdx.x, pb = blockIdx.y, b = blockIdx.z;
    for (int idx = tid; idx < 1024; idx += 256) {
        const int f = idx >> 5, c = idx & 31;
        const float* kp = K + (f * 32 + c) * 9;
        float k00 = kp[0], k01 = kp[1], k02 = kp[2];
        float k10 = kp[3], k11 = kp[4], k12 = kp[5];
        float k20 = kp[6], k21 = kp[7], k22 = kp[8];
        float t[4][3];
        t[0][0] = k00; t[0][1] = k01; t[0][2] = k02;
        t[1][0] = 0.5f * (k00 + k10 + k20); t[1][1] = 0.5f * (k01 + k11 + k21); t[1][2] = 0.5f * (k02 + k12 + k22);
        t[2][0] = 0.5f * (k00 - k10 + k20); t[2][1] = 0.5f * (k01 - k11 + k21); t[2][2] = 0.5f * (k02 - k12 + k22);
        t[3][0] = k20; t[3][1] = k21; t[3][2] = k22;
        const int ubase = ((c >> 3) * 32 + f) * 8 + (c & 7);
        #pragma unroll
        for (int i = 0; i < 4; i++) {
            float a0 = t[i][0], a1 = t[i][1], a2 = t[i][2];
            Ul[(i * 4 + 0) * 1024 + ubase] = f2bf16_rne(a0);
            Ul[(i * 4 + 1) * 1024 + ubase] = f2bf16_rne(0.5f * (a0 + a1 + a2));
            Ul[(i * 4 + 2) * 1024 + ubase] = f2bf16_rne(0.5f * (a0 - a1 + a2));
            Ul[(i * 4 + 3) * 1024 + ubase] = f2bf16_rne(a2);
        }
    }
    const int y0 = pb * 8, x0 = qb * 16;
    for (int s = tid; s < 2880; s += 256) {
        const int c = s / 90;
        const int r = s % 90;
        const int row = r / 9, seg = r % 9;
        const float* gp = X + ((b * 32 + c) * 258 + (y0 + row)) * 258 + x0 + seg * 2;
        float2 g = *(const float2*)gp;
        uint32_t packed = (uint32_t)f2bf16_rne(g.x) | ((uint32_t)f2bf16_rne(g.y) << 16);
        *(uint32_t*)&Pl[c * 242 + row * 24 + seg * 2] = packed;
    }
    __syncthreads();
    for (int idx = tid; idx < 1024; idx += 256) {
        const int c = idx & 31, tt = idx >> 5;
        const int tr = tt >> 3, tc = tt & 7;
        const uint16_t* pp = &Pl[c * 242 + (tr * 2) * 24 + tc * 2];
        float d[4][4];
        #pragma unroll
        for (int j = 0; j < 4; j++) {
            uint32_t w0 = *(const uint32_t*)&pp[j * 24];
            uint32_t w1 = *(const uint32_t*)&pp[j * 24 + 2];
            d[j][0] = bflo(w0); d[j][1] = bfhi(w0);
            d[j][2] = bflo(w1); d[j][3] = bfhi(w1);
        }
        float bt[4][4];
        #pragma unroll
        for (int k = 0; k < 4; k++) {
            bt[0][k] = d[0][k] - d[2][k];
            bt[1][k] = d[1][k] + d[2][k];
            bt[2][k] = d[2][k] - d[1][k];
            bt[3][k] = d[1][k] - d[3][k];
        }
        const int vbase = (((tt >> 4) * 4 + (c >> 3)) * 16 + (tt & 15)) * 8 + (c & 7);
        #pragma unroll
        for (int i = 0; i < 4; i++) {
            float b0 = bt[i][0], b1 = bt[i][1], b2 = bt[i][2], b3 = bt[i][3];
            Vl[(i * 4 + 0) * 1024 + vbase] = f2bf16_rne(b0 - b2);
            Vl[(i * 4 + 1) * 1024 + vbase] = f2bf16_rne(b1 + b2);
            Vl[(i * 4 + 2) * 1024 + vbase] = f2bf16_rne(b2 - b1);
            Vl[(i * 4 + 3) * 1024 + vbase] = f2bf16_rne(b1 - b3);
        }
    }
    __syncthreads();
    const int wave = tid >> 6, lane = tid & 63;
    const int fh = wave & 1, tb = wave >> 1;
    const int l15 = lane & 15, lq = lane >> 4;
    f32x4 acc[16];
    #pragma unroll
    for (int p = 0; p < 16; p++) acc[p] = (f32x4){0.f, 0.f, 0.f, 0.f};
    #pragma unroll
    for (int p = 0; p < 16; p++) {
        bf16x8 a = *(const bf16x8*)&Ul[p * 1024 + (lq * 32 + fh * 16 + l15) * 8];
        bf16x8 bv = *(const bf16x8*)&Vl[p * 1024 + ((tb * 4 + lq) * 16 + l15) * 8];
        acc[p] = __builtin_amdgcn_mfma_f32_16x16x32_bf16(a, bv, acc[p], 0, 0, 0);
    }
    #pragma unroll
    for (int r = 0; r < 4; r++) {
        const int f = fh * 16 + lq * 4 + r;
        const int t = tb * 16 + l15;
        const int tr = t >> 3, tc = t & 7;
        const int p = pb * 4 + tr, q = qb * 8 + tc;
        float m[4][4];
        #pragma unroll
        for (int i = 0; i < 4; i++)
            #pragma unroll
            for (int l = 0; l < 4; l++)
                m[i][l] = acc[i * 4 + l][r];
        float s0[4], s1[4];
        #pragma unroll
        for (int k = 0; k < 4; k++) {
            s0[k] = m[0][k] + m[1][k] + m[2][k];
            s1[k] = m[1][k] - m[2][k] - m[3][k];
        }
        float* op = out + ((size_t)(b * 32 + f) * 256 + 2 * p) * 256 + 2 * q;
        *(float2*)op = make_float2(s0[0] + s0[1] + s0[2], s0[1] - s0[2] - s0[3]);
        *(float2*)(op + 256) = make_float2(s1[0] + s1[1] + s1[2], s1[1] - s1[2] - s1[3]);
    }
}

extern "C" void kernel_launch(void* const* d_in, const int* in_sizes, int n_in,
                              void* d_out, int out_size, void* d_ws, size_t ws_size,
                              hipStream_t stream) {
    const float* X = (const float*)d_in[0];
    const float* K = (const float*)d_in[1];
    float* out = (float*)d_out;
    dim3 grid(16, 32, 16);
    if (ws_size >= 32768) {
        wg_filter<<<2, 256, 0, stream>>>(K, (uint32_t*)d_ws);
        wg_main<<<grid, 256, 0, stream>>>(X, (const uint16_t*)d_ws, out);
    } else {
        winograd_fallback<<<grid, 256, 0, stream>>>(X, K, out);
    }
}